// Round 1
// baseline (87.656 us; speedup 1.0000x reference)
//
#include <hip/hip_runtime.h>

typedef float f32x4 __attribute__((ext_vector_type(4)));
typedef __bf16 bf16x8 __attribute__((ext_vector_type(8)));

#define BN_EPS 1e-5f

__device__ __forceinline__ unsigned short f2bf(float x) {
  union { float f; unsigned u; } v; v.f = x;
  unsigned r = v.u + 0x7fffu + ((v.u >> 16) & 1u);
  return (unsigned short)(r >> 16);
}

// ---------------- prep: fold BN into weights (bf16) + biases (fp32) ----------------
__global__ void prep_kernel(const float* __restrict__ W1, const float* __restrict__ b1,
                            const float* __restrict__ g1, const float* __restrict__ bt1,
                            const float* __restrict__ mu1, const float* __restrict__ v1,
                            const float* __restrict__ W2, const float* __restrict__ b2,
                            const float* __restrict__ g2, const float* __restrict__ bt2,
                            const float* __restrict__ mu2, const float* __restrict__ v2,
                            unsigned short* __restrict__ W1b, unsigned short* __restrict__ W2b,
                            float* __restrict__ bias1, float* __restrict__ bias2) {
  int tid = blockIdx.x * 256 + threadIdx.x;
  if (tid < 98304) {                       // W1: 256 x 384
    int o = tid / 384;
    float s = g1[o] * rsqrtf(v1[o] + BN_EPS);
    W1b[tid] = f2bf(W1[tid] * s);
    if (tid < 256) bias1[tid] = (b1[tid] - mu1[tid]) * (g1[tid] * rsqrtf(v1[tid] + BN_EPS)) + bt1[tid];
  } else if (tid < 98304 + 32768) {        // W2: 128 x 256
    int t = tid - 98304;
    int o = t / 256;
    float s = g2[o] * rsqrtf(v2[o] + BN_EPS);
    W2b[t] = f2bf(W2[t] * s);
    if (t < 128) bias2[t] = (b2[t] - mu2[t]) * (g2[t] * rsqrtf(v2[t] + BN_EPS)) + bt2[t];
  }
}

// ---------------- fused: 3NN + interpolate + concat + MLP(2 layers) ----------------
// B=16, n=4096, m=1024, C1=128, C2=256, Cin=384, H1=256, H2=128
// 64 points per block, 256 threads (4 waves).
__global__ __launch_bounds__(256, 2)
void fp_fused_kernel(const float* __restrict__ unknown, const float* __restrict__ known,
                     const float* __restrict__ unknow_feats, const float* __restrict__ known_feats,
                     const unsigned short* __restrict__ W1b, const unsigned short* __restrict__ W2b,
                     const float* __restrict__ bias1, const float* __restrict__ bias2,
                     float* __restrict__ out) {
  __shared__ float kxyz[3072];                       // known xyz of this batch (12 KB)
  __shared__ float sd[64 * 12];                      // per-chunk top3 dists
  __shared__ int   si[64 * 12];                      // per-chunk top3 idx
  __shared__ float w_s[64 * 3];
  __shared__ int   i_s[64 * 3];
  __shared__ __align__(16) unsigned char xbuf[64 * 768];  // x tile (bf16 64x384), later y tile (64x256)

  int bid = blockIdx.x;
  int swz = ((bid & 7) << 7) | (bid >> 3);           // XCD-contiguous remap (1024 blocks, bijective)
  int b   = swz >> 6;
  int i0  = (swz & 63) << 6;

  int tid = threadIdx.x;
  int l = tid & 63;
  int q = tid >> 6;                                  // wave id (uniform per wave)

  // stage known xyz, coalesced
  for (int t = tid; t < 3072; t += 256) kxyz[t] = known[b * 3072 + t];

  int pi = i0 + l;
  float ux = unknown[(b * 4096 + pi) * 3 + 0];
  float uy = unknown[(b * 4096 + pi) * 3 + 1];
  float uz = unknown[(b * 4096 + pi) * 3 + 2];
  __syncthreads();

  // ---- per-thread top-3 over 256-candidate chunk q (subtract form, fp32) ----
  float d0 = 3.0e38f, d1 = 3.0e38f, d2 = 3.0e38f;
  int   j0 = 0, j1 = 0, j2 = 0;
  int jbase = q << 8;
  for (int jj = 0; jj < 256; ++jj) {
    int j = jbase + jj;
    float dx = ux - kxyz[j * 3 + 0];
    float dy = uy - kxyz[j * 3 + 1];
    float dz = uz - kxyz[j * 3 + 2];
    float d = dx * dx + dy * dy + dz * dz;
    bool c2 = d < d2, c1 = d < d1, c0 = d < d0;
    d2 = c1 ? d1 : (c2 ? d : d2);  j2 = c1 ? j1 : (c2 ? j : j2);
    d1 = c0 ? d0 : (c1 ? d : d1);  j1 = c0 ? j0 : (c1 ? j : j1);
    d0 = c0 ? d : d0;              j0 = c0 ? j : j0;
  }
  int sb = l * 12 + q * 3;
  sd[sb] = d0; sd[sb + 1] = d1; sd[sb + 2] = d2;
  si[sb] = j0; si[sb + 1] = j1; si[sb + 2] = j2;
  __syncthreads();

  // ---- merge 4 partial top-3s (chunk-major order keeps lowest-index-on-tie) ----
  if (tid < 64) {
    float m0 = 3.0e38f, m1 = 3.0e38f, m2 = 3.0e38f;
    int   n0 = 0, n1 = 0, n2 = 0;
    for (int e = 0; e < 12; ++e) {
      float d = sd[tid * 12 + e]; int j = si[tid * 12 + e];
      bool c2 = d < m2, c1 = d < m1, c0 = d < m0;
      m2 = c1 ? m1 : (c2 ? d : m2);  n2 = c1 ? n1 : (c2 ? j : n2);
      m1 = c0 ? m0 : (c1 ? d : m1);  n1 = c0 ? n0 : (c1 ? j : n1);
      m0 = c0 ? d : m0;              n0 = c0 ? j : n0;
    }
    float r0 = 1.0f / (m0 + 1e-10f);
    float r1 = 1.0f / (m1 + 1e-10f);
    float r2 = 1.0f / (m2 + 1e-10f);
    float rs = 1.0f / (r0 + r1 + r2);
    w_s[tid * 3 + 0] = r0 * rs; i_s[tid * 3 + 0] = n0;
    w_s[tid * 3 + 1] = r1 * rs; i_s[tid * 3 + 1] = n1;
    w_s[tid * 3 + 2] = r2 * rs; i_s[tid * 3 + 2] = n2;
  }
  __syncthreads();

  // ---- interpolate -> x cols [0,256), bf16, XOR-swizzled LDS ----
  {
    int pp = tid >> 6;                               // wave id: one point per wave per iter
    int cq = tid & 63;                               // float4 column
    const float4* kf = (const float4*)(known_feats + (size_t)b * 1024 * 256);
    for (int po = 0; po < 16; ++po) {
      int p = po * 4 + pp;
      int ia = i_s[p * 3 + 0], ib = i_s[p * 3 + 1], ic = i_s[p * 3 + 2];
      float wa = w_s[p * 3 + 0], wb = w_s[p * 3 + 1], wc = w_s[p * 3 + 2];
      float4 va = kf[ia * 64 + cq];
      float4 vb = kf[ib * 64 + cq];
      float4 vc = kf[ic * 64 + cq];
      ushort4 h;
      h.x = f2bf(wa * va.x + wb * vb.x + wc * vc.x);
      h.y = f2bf(wa * va.y + wb * vb.y + wc * vc.y);
      h.z = f2bf(wa * va.z + wb * vb.z + wc * vc.z);
      h.w = f2bf(wa * va.w + wb * vb.w + wc * vc.w);
      int byte = p * 768 + cq * 8;
      byte ^= (p & 7) << 4;
      *(ushort4*)(xbuf + byte) = h;
    }
  }
  // ---- copy unknow_feats -> x cols [256,384) ----
  {
    int pp = tid >> 5;                               // 0..7
    int cq = tid & 31;                               // float4 column of 32
    const float4* uf = (const float4*)(unknow_feats + ((size_t)b * 4096 + i0) * 128);
    for (int po = 0; po < 8; ++po) {
      int p = po * 8 + pp;
      float4 v = uf[p * 32 + cq];
      ushort4 h;
      h.x = f2bf(v.x); h.y = f2bf(v.y); h.z = f2bf(v.z); h.w = f2bf(v.w);
      int byte = p * 768 + 512 + cq * 8;
      byte ^= (p & 7) << 4;
      *(ushort4*)(xbuf + byte) = h;
    }
  }
  __syncthreads();

  // ---- GEMM1: (64x384) x (384->256), wave q owns cols [64q, 64q+64) ----
  int lr = l & 15;
  int lk = l >> 4;
  f32x4 acc[4][4];
  #pragma unroll
  for (int m = 0; m < 4; ++m)
    #pragma unroll
    for (int n = 0; n < 4; ++n) acc[m][n] = (f32x4){0.f, 0.f, 0.f, 0.f};

  for (int kk = 0; kk < 12; ++kk) {
    int kb = kk * 32 + lk * 8;                       // bf16 k index
    bf16x8 a[4];
    #pragma unroll
    for (int m = 0; m < 4; ++m) {
      int row = m * 16 + lr;
      int byte = row * 768 + kb * 2;
      byte ^= (row & 7) << 4;
      a[m] = *(const bf16x8*)(xbuf + byte);
    }
    #pragma unroll
    for (int n = 0; n < 4; ++n) {
      int wr = q * 64 + n * 16 + lr;
      bf16x8 bb = *(const bf16x8*)(W1b + wr * 384 + kb);
      #pragma unroll
      for (int m = 0; m < 4; ++m)
        acc[m][n] = __builtin_amdgcn_mfma_f32_16x16x32_bf16(a[m], bb, acc[m][n], 0, 0, 0);
    }
  }

  float bs1[4];
  #pragma unroll
  for (int n = 0; n < 4; ++n) bs1[n] = bias1[q * 64 + n * 16 + lr];

  __syncthreads();   // all xbuf reads done; safe to overwrite with y tile
  #pragma unroll
  for (int m = 0; m < 4; ++m)
    #pragma unroll
    for (int n = 0; n < 4; ++n)
      #pragma unroll
      for (int i = 0; i < 4; ++i) {
        int r = m * 16 + lk * 4 + i;
        int c = q * 64 + n * 16 + lr;
        float val = fmaxf(acc[m][n][i] + bs1[n], 0.0f);
        int byte = r * 512 + c * 2;
        byte ^= (r & 7) << 4;
        *(unsigned short*)(xbuf + byte) = f2bf(val);
      }
  __syncthreads();

  // ---- GEMM2: (64x256) x (256->128), wave q owns cols [32q, 32q+32) ----
  f32x4 acc2[4][2];
  #pragma unroll
  for (int m = 0; m < 4; ++m)
    #pragma unroll
    for (int n = 0; n < 2; ++n) acc2[m][n] = (f32x4){0.f, 0.f, 0.f, 0.f};

  for (int kk = 0; kk < 8; ++kk) {
    int kb = kk * 32 + lk * 8;
    bf16x8 a[4];
    #pragma unroll
    for (int m = 0; m < 4; ++m) {
      int row = m * 16 + lr;
      int byte = row * 512 + kb * 2;
      byte ^= (row & 7) << 4;
      a[m] = *(const bf16x8*)(xbuf + byte);
    }
    #pragma unroll
    for (int n = 0; n < 2; ++n) {
      int wr = q * 32 + n * 16 + lr;
      bf16x8 bb = *(const bf16x8*)(W2b + wr * 256 + kb);
      #pragma unroll
      for (int m = 0; m < 4; ++m)
        acc2[m][n] = __builtin_amdgcn_mfma_f32_16x16x32_bf16(a[m], bb, acc2[m][n], 0, 0, 0);
    }
  }

  float bs2[2];
  #pragma unroll
  for (int n = 0; n < 2; ++n) bs2[n] = bias2[q * 32 + n * 16 + lr];

  float* outb = out + ((size_t)b * 4096 + i0) * 128;
  #pragma unroll
  for (int m = 0; m < 4; ++m)
    #pragma unroll
    for (int n = 0; n < 2; ++n)
      #pragma unroll
      for (int i = 0; i < 4; ++i) {
        int r = m * 16 + lk * 4 + i;
        int c = q * 32 + n * 16 + lr;
        outb[r * 128 + c] = fmaxf(acc2[m][n][i] + bs2[n], 0.0f);
      }
}

extern "C" void kernel_launch(void* const* d_in, const int* in_sizes, int n_in,
                              void* d_out, int out_size, void* d_ws, size_t ws_size,
                              hipStream_t stream) {
  const float* unknown      = (const float*)d_in[0];
  const float* known        = (const float*)d_in[1];
  const float* unknow_feats = (const float*)d_in[2];
  const float* known_feats  = (const float*)d_in[3];
  const float* W1  = (const float*)d_in[4];
  const float* b1  = (const float*)d_in[5];
  const float* g1  = (const float*)d_in[6];
  const float* bt1 = (const float*)d_in[7];
  const float* mu1 = (const float*)d_in[8];
  const float* v1  = (const float*)d_in[9];
  const float* W2  = (const float*)d_in[10];
  const float* b2  = (const float*)d_in[11];
  const float* g2  = (const float*)d_in[12];
  const float* bt2 = (const float*)d_in[13];
  const float* mu2 = (const float*)d_in[14];
  const float* v2  = (const float*)d_in[15];

  unsigned short* W1b = (unsigned short*)d_ws;       // 98304 bf16
  unsigned short* W2b = W1b + 98304;                 // 32768 bf16
  float* bias1 = (float*)(W2b + 32768);              // 256 f32 (offset 262144 B)
  float* bias2 = bias1 + 256;                        // 128 f32

  prep_kernel<<<512, 256, 0, stream>>>(W1, b1, g1, bt1, mu1, v1,
                                       W2, b2, g2, bt2, mu2, v2,
                                       W1b, W2b, bias1, bias2);
  fp_fused_kernel<<<1024, 256, 0, stream>>>(unknown, known, unknow_feats, known_feats,
                                            W1b, W2b, bias1, bias2, (float*)d_out);
}